// Round 6
// baseline (146.354 us; speedup 1.0000x reference)
//
#include <hip/hip_runtime.h>
#include <hip/hip_bf16.h>

// Problem constants (MultiHeadAttention, B=2, S=2048, D=1024, H=16)
#define B_SZ    2
#define S_LEN   2048
#define D_MODEL 1024
#define H_NUM   16
#define DH      64
#define M_TOT   (B_SZ * S_LEN)   // 4096 tokens

// scale = S^-0.5 (faithful bug) folded with log2(e) for exp2-domain softmax
#define QSCALE (0.022097086912079608f * 1.4426950408889634f)

typedef __attribute__((ext_vector_type(8)))  short          bf16x8;
typedef __attribute__((ext_vector_type(4)))  float          f32x4;
typedef __attribute__((ext_vector_type(16))) float          f32x16;
typedef __attribute__((ext_vector_type(8)))  unsigned short u16x8;
typedef __attribute__((ext_vector_type(4)))  unsigned short u16x4;

__device__ inline unsigned short f2bf(float f) {
  unsigned int u = __float_as_uint(f);
  u += 0x7fffu + ((u >> 16) & 1u);   // RNE (no NaN inputs here)
  return (unsigned short)(u >> 16);
}

__device__ inline float fexp2(float x) {
#if __has_builtin(__builtin_amdgcn_exp2f)
  return __builtin_amdgcn_exp2f(x);
#else
  return exp2f(x);
#endif
}

__device__ inline unsigned cvt_pk_bf16(float lo, float hi) {
  unsigned r;
  asm("v_cvt_pk_bf16_f32 %0, %1, %2" : "=v"(r) : "v"(lo), "v"(hi));
  return r;
}

// async global->LDS, 16B per lane. LDS dest = wave-uniform base + lane*16.
__device__ inline void gload16(const void* g, void* l) {
  __builtin_amdgcn_global_load_lds(
      (const __attribute__((address_space(1))) void*)g,
      (__attribute__((address_space(3))) void*)l, 16, 0, 0);
}

// ---------------------------------------------------------------------------
// fp32 -> bf16 conversion for x, Wq, Wk, Wv, Wo (8M elements, 8 per thread)
// ---------------------------------------------------------------------------
__global__ __launch_bounds__(256) void to_bf16_all(
    const float* __restrict__ x, const float* __restrict__ wq,
    const float* __restrict__ wk, const float* __restrict__ wv,
    const float* __restrict__ wo, unsigned short* __restrict__ xb,
    unsigned short* __restrict__ wqb, unsigned short* __restrict__ wkb,
    unsigned short* __restrict__ wvb, unsigned short* __restrict__ wob) {
  const size_t i = ((size_t)blockIdx.x * 256 + threadIdx.x) * 8;
  const float* src;
  unsigned short* dst;
  size_t off;
  if (i < 4194304)      { src = x;  dst = xb;  off = i; }
  else if (i < 5242880) { src = wq; dst = wqb; off = i - 4194304; }
  else if (i < 6291456) { src = wk; dst = wkb; off = i - 5242880; }
  else if (i < 7340032) { src = wv; dst = wvb; off = i - 6291456; }
  else                  { src = wo; dst = wob; off = i - 7340032; }
  f32x4 a = *(const f32x4*)(src + off);
  f32x4 b = *(const f32x4*)(src + off + 4);
  u16x8 o;
#pragma unroll
  for (int j = 0; j < 4; j++) { o[j] = f2bf(a[j]); o[4 + j] = f2bf(b[j]); }
  *(u16x8*)(dst + off) = o;
}

// ---------------------------------------------------------------------------
// bf16 NT-GEMM core: acc += A[128 rows @ mbase] * W[128 rows @ nbase]^T.
// Double-buffered global_load_lds(16) staging with counted vmcnt(4) + raw
// s_barrier pairs (prefetch stays in flight across barriers; no full drain).
// Linear LDS + XOR chunk swizzle (pre-swizzled source, swizzled read).
// ---------------------------------------------------------------------------
__device__ __forceinline__ void gemm_core(const unsigned short* __restrict__ A,
                                          const unsigned short* __restrict__ W,
                                          unsigned short (*Al)[128][32],
                                          unsigned short (*Bl)[128][32],
                                          int mbase, int nbase,
                                          f32x4 acc[4][4]) {
  const int tid  = threadIdx.x;
  const int lane = tid & 63;
  const int wid  = tid >> 6;
  const int wr   = wid >> 1, wc = wid & 1;
  const int g    = lane >> 4, lr = lane & 15;

  const int r0 = tid >> 2;                        // 0..63 staging row
  const int cg = (tid & 3) ^ ((tid >> 3) & 3);    // swizzled source chunk

  const unsigned short* Abase = A + (size_t)(mbase + r0) * D_MODEL + cg * 8;
  const unsigned short* Wbase = W + (size_t)(nbase + r0) * D_MODEL + cg * 8;
  char* ldsA0 = (char*)Al + wid * 1024;  // buffer stride 8192
  char* ldsB0 = (char*)Bl + wid * 1024;

  // prologue: tile 0 -> buf 0
  gload16(Abase, ldsA0);
  gload16(Abase + (size_t)64 * D_MODEL, ldsA0 + 4096);
  gload16(Wbase, ldsB0);
  gload16(Wbase + (size_t)64 * D_MODEL, ldsB0 + 4096);

  const int NKT = D_MODEL / 32;
  for (int kt = 0; kt < NKT; ++kt) {
    const int cur = kt & 1;
    if (kt + 1 < NKT) {  // prefetch next tile into other buffer
      const unsigned short* As = Abase + (kt + 1) * 32;
      const unsigned short* Ws = Wbase + (kt + 1) * 32;
      char* la = ldsA0 + (cur ^ 1) * 8192;
      char* lb = ldsB0 + (cur ^ 1) * 8192;
      gload16(As, la);
      gload16(As + (size_t)64 * D_MODEL, la + 4096);
      gload16(Ws, lb);
      gload16(Ws + (size_t)64 * D_MODEL, lb + 4096);
      asm volatile("s_waitcnt vmcnt(4)" ::: "memory");  // tile kt landed
    } else {
      asm volatile("s_waitcnt vmcnt(0)" ::: "memory");
    }
    __builtin_amdgcn_s_barrier();

    bf16x8 af[4], bfr[4];
#pragma unroll
    for (int i = 0; i < 4; i++) {
      const int ra = wr * 64 + i * 16 + lr;
      af[i] = *(const bf16x8*)&Al[cur][ra][(g ^ ((ra >> 1) & 3)) * 8];
      const int rb = wc * 64 + i * 16 + lr;
      bfr[i] = *(const bf16x8*)&Bl[cur][rb][(g ^ ((rb >> 1) & 3)) * 8];
    }
    __builtin_amdgcn_s_setprio(1);
#pragma unroll
    for (int i = 0; i < 4; i++)
#pragma unroll
      for (int j = 0; j < 4; j++)
        acc[i][j] = __builtin_amdgcn_mfma_f32_16x16x32_bf16(af[i], bfr[j],
                                                            acc[i][j], 0, 0, 0);
    __builtin_amdgcn_s_setprio(0);
    asm volatile("" ::: "memory");
    __builtin_amdgcn_s_barrier();  // buf[cur] free for next prefetch
  }
}

// ---------------------------------------------------------------------------
// Fused Q/K/V projection. grid (N/128, M/128, 3); z picks weight + epilogue.
// z=0 -> Q bf16 [M][D] PRE-SCALED by QSCALE; z=1 -> K bf16 [M][D];
// z=2 -> V transposed Vt[((b*H+h)*DH+d)*S + s].
// ---------------------------------------------------------------------------
__global__ __launch_bounds__(256) void gemm_qkv(
    const unsigned short* __restrict__ xb, const unsigned short* __restrict__ wqb,
    const unsigned short* __restrict__ wkb, const unsigned short* __restrict__ wvb,
    unsigned short* __restrict__ qb, unsigned short* __restrict__ kb,
    unsigned short* __restrict__ vt) {
  __shared__ unsigned short Al[2][128][32];
  __shared__ unsigned short Bl[2][128][32];
  const int z = blockIdx.z;
  const unsigned short* W = (z == 0) ? wqb : (z == 1) ? wkb : wvb;
  unsigned short* dst = (z == 0) ? qb : (z == 1) ? kb : vt;
  const float sc = (z == 0) ? QSCALE : 1.0f;

  f32x4 acc[4][4];
#pragma unroll
  for (int i = 0; i < 4; i++)
#pragma unroll
    for (int j = 0; j < 4; j++) acc[i][j] = (f32x4){0.f, 0.f, 0.f, 0.f};

  const int mbase = blockIdx.y * 128, nbase = blockIdx.x * 128;
  gemm_core(xb, W, Al, Bl, mbase, nbase, acc);

  const int lane = threadIdx.x & 63, wid = threadIdx.x >> 6;
  const int wr = wid >> 1, wc = wid & 1, g = lane >> 4, lr = lane & 15;
#pragma unroll
  for (int i = 0; i < 4; i++) {
#pragma unroll
    for (int j = 0; j < 4; j++) {
      const int mg0 = mbase + wr * 64 + i * 16 + g * 4;  // + r
      const int ng  = nbase + wc * 64 + j * 16 + lr;
      if (z < 2) {
#pragma unroll
        for (int r = 0; r < 4; r++)
          dst[(size_t)(mg0 + r) * D_MODEL + ng] = f2bf(acc[i][j][r] * sc);
      } else {
        const int hh = ng >> 6, dd = ng & 63;
        const int bb = mg0 >> 11, ss = mg0 & 2047;  // mg0 mult of 4
        u16x4 pk;
#pragma unroll
        for (int r = 0; r < 4; r++) pk[r] = f2bf(acc[i][j][r]);
        *(u16x4*)&dst[((size_t)((bb * H_NUM + hh) * DH + dd)) * S_LEN + ss] = pk;
      }
    }
  }
}

// ---------------------------------------------------------------------------
// Output projection: out[M][D] fp32 = cx * Wo^T + bo
// ---------------------------------------------------------------------------
__global__ __launch_bounds__(256) void gemm_out(
    const unsigned short* __restrict__ cx, const unsigned short* __restrict__ wob,
    float* __restrict__ out, const float* __restrict__ bo) {
  __shared__ unsigned short Al[2][128][32];
  __shared__ unsigned short Bl[2][128][32];
  f32x4 acc[4][4];
#pragma unroll
  for (int i = 0; i < 4; i++)
#pragma unroll
    for (int j = 0; j < 4; j++) acc[i][j] = (f32x4){0.f, 0.f, 0.f, 0.f};

  const int mbase = blockIdx.y * 128, nbase = blockIdx.x * 128;
  gemm_core(cx, wob, Al, Bl, mbase, nbase, acc);

  const int lane = threadIdx.x & 63, wid = threadIdx.x >> 6;
  const int wr = wid >> 1, wc = wid & 1, g = lane >> 4, lr = lane & 15;
#pragma unroll
  for (int i = 0; i < 4; i++) {
#pragma unroll
    for (int j = 0; j < 4; j++) {
      const int mg0 = mbase + wr * 64 + i * 16 + g * 4;
      const int ng  = nbase + wc * 64 + j * 16 + lr;
      const float bv = bo[ng];
#pragma unroll
      for (int r = 0; r < 4; r++)
        out[(size_t)(mg0 + r) * D_MODEL + ng] = acc[i][j][r] + bv;
    }
  }
}

// ---------------------------------------------------------------------------
// Causal flash attention v4: wave-autonomous, K/V direct-to-register.
// grid = 2048 1-wave blocks (64 q-tiles of 32 rows x 32 bh), longest first.
// In the swapped-operand 32x32 structure every K/V element is consumed by
// exactly one lane -> no LDS staging, no barriers. KVBLK=32, A/B register
// double-buffer (named sets; compiler emits counted vmcnt automatically).
// bid%8 == head%8 pins each head's K/V to one XCD's L2.
// ---------------------------------------------------------------------------
__global__ __launch_bounds__(64, 3) void attn_v4(
    const unsigned short* __restrict__ qb, const unsigned short* __restrict__ kb,
    const unsigned short* __restrict__ vt, unsigned short* __restrict__ cx) {
  __shared__ unsigned short Tl[32][72];  // epilogue transpose only (4.6 KB)

  const int lane = threadIdx.x;          // 0..63
  const int hi   = lane >> 5;
  const int lq   = lane & 31;
  const int bid  = blockIdx.x;
  const int t    = 63 - (bid >> 5);      // q-tile index (32 rows), longest first
  const int bh   = bid & 31;
  const int b    = bh >> 4, h = bh & 15;

  const int qg0  = t * 32;               // q base within sequence
  const int tok0 = b * S_LEN + qg0;

  // per-lane base pointers (16B-aligned)
  const unsigned short* kptr =
      kb + (size_t)(b * S_LEN + lq) * D_MODEL + h * DH + hi * 8;
  const unsigned short* vptr =
      vt + ((size_t)((b * H_NUM + h) * DH + lq)) * S_LEN + hi * 8;

  // Q fragments: B-operand, col q = lq, k = hi*8+j within dh-slice ks
  bf16x8 qf[4];
  {
    const unsigned short* qrow =
        qb + (size_t)(tok0 + lq) * D_MODEL + h * DH + hi * 8;
#pragma unroll
    for (int ks = 0; ks < 4; ks++) qf[ks] = *(const bf16x8*)(qrow + ks * 16);
  }

  f32x16 ctx0, ctx1;
#pragma unroll
  for (int r = 0; r < 16; r++) { ctx0[r] = 0.f; ctx1[r] = 0.f; }
  float m_run = -1e30f, l_run = 0.f;

  const int nkt = t + 1;  // causal: 32-wide kv tiles 0..t

  // K frags: kf[ks] = K[kv=lq][dh = ks*16 + hi*8 + j]
  // V frags: vf[s2*2+dh] = Vt[d = dh*32+lq][kv = tile*32 + s2*16 + hi*8 + j]
  auto LOADT = [&](bf16x8* kf, bf16x8* vf, int tile) {
    const unsigned short* ks_ = kptr + (size_t)(tile * 32) * D_MODEL;
#pragma unroll
    for (int ks = 0; ks < 4; ks++) kf[ks] = *(const bf16x8*)(ks_ + ks * 16);
#pragma unroll
    for (int s2 = 0; s2 < 2; s2++)
#pragma unroll
      for (int dh2 = 0; dh2 < 2; dh2++)
        vf[s2 * 2 + dh2] = *(const bf16x8*)(vptr + (size_t)(dh2 * 32) * S_LEN +
                                            tile * 32 + s2 * 16);
  };

  auto COMPUTE = [&](const bf16x8* kf, const bf16x8* vf, int tile) {
    // S^T = K Q^T : lane holds q=lq, 16 of 32 kv (partner lane^32 has rest)
    f32x16 s;
#pragma unroll
    for (int r = 0; r < 16; r++) s[r] = 0.f;
    __builtin_amdgcn_s_setprio(1);
#pragma unroll
    for (int ks = 0; ks < 4; ks++)
      s = __builtin_amdgcn_mfma_f32_32x32x16_bf16(kf[ks], qf[ks], s, 0, 0, 0);
    __builtin_amdgcn_s_setprio(0);

    if (tile == t) {  // diagonal tile: causal mask (uniform branch)
      const int relq = lq - 4 * hi;
#pragma unroll
      for (int r = 0; r < 16; r++) {
        const int ko = (r & 3) + 8 * (r >> 2);
        s[r] = (ko > relq) ? -1e30f : s[r];
      }
    }

    float pmax = s[0];
#pragma unroll
    for (int r = 1; r < 16; r++) pmax = fmaxf(pmax, s[r]);
    pmax = fmaxf(pmax, __shfl_xor(pmax, 32));

    if (__any(pmax > m_run + 8.0f)) {  // defer-max (T13), log2 domain
      const float mnew = fmaxf(m_run, pmax);
      const float al   = fexp2(m_run - mnew);
      m_run = mnew;
      l_run *= al;
#pragma unroll
      for (int r = 0; r < 16; r++) { ctx0[r] *= al; ctx1[r] *= al; }
    }

    float lsum = 0.f;
#pragma unroll
    for (int s2 = 0; s2 < 2; s2++) {
      float p[8];
#pragma unroll
      for (int j = 0; j < 8; j++) {
        p[j] = fexp2(s[s2 * 8 + j] - m_run);
        lsum += p[j];
      }
      // pack pairs, exchange halves: lane keeps kv sub-slice hi*8..hi*8+7
      const unsigned w01 = cvt_pk_bf16(p[0], p[1]);
      const unsigned w23 = cvt_pk_bf16(p[2], p[3]);
      const unsigned w45 = cvt_pk_bf16(p[4], p[5]);
      const unsigned w67 = cvt_pk_bf16(p[6], p[7]);
      const unsigned x01 = __shfl_xor(w01, 32);
      const unsigned x23 = __shfl_xor(w23, 32);
      const unsigned x45 = __shfl_xor(w45, 32);
      const unsigned x67 = __shfl_xor(w67, 32);
      union { unsigned u[4]; bf16x8 v; } pw;
      pw.u[0] = hi ? x45 : w01;
      pw.u[1] = hi ? x67 : w23;
      pw.u[2] = hi ? w45 : x01;
      pw.u[3] = hi ? w67 : x23;
      __builtin_amdgcn_s_setprio(1);
      ctx0 = __builtin_amdgcn_mfma_f32_32x32x16_bf16(vf[s2 * 2 + 0], pw.v,
                                                     ctx0, 0, 0, 0);
      ctx1 = __builtin_amdgcn_mfma_f32_32x32x16_bf16(vf[s2 * 2 + 1], pw.v,
                                                     ctx1, 0, 0, 0);
      __builtin_amdgcn_s_setprio(0);
    }
    l_run += lsum;
  };

  // software pipeline with named A/B register sets (no runtime indexing)
  bf16x8 kA[4], vA[4], kB[4], vB[4];
  LOADT(kA, vA, 0);
  int kt = 0;
  while (true) {
    if (kt + 1 < nkt) LOADT(kB, vB, kt + 1);
    COMPUTE(kA, vA, kt);
    if (++kt >= nkt) break;
    if (kt + 1 < nkt) LOADT(kA, vA, kt + 1);
    COMPUTE(kB, vB, kt);
    if (++kt >= nkt) break;
  }

  // ---- epilogue: normalize (per-lane scalar), transpose via LDS, store ----
  const float lfull = l_run + __shfl_xor(l_run, 32);
  const float inv   = 1.0f / lfull;
#pragma unroll
  for (int rp = 0; rp < 8; rp++) {
    const int r  = rp * 2;
    const int d0 = (r & 3) + 8 * (r >> 2) + 4 * hi;  // even; pair (d0, d0+1)
    *(unsigned*)&Tl[lq][d0] = cvt_pk_bf16(ctx0[r] * inv, ctx0[r + 1] * inv);
    *(unsigned*)&Tl[lq][32 + d0] =
        cvt_pk_bf16(ctx1[r] * inv, ctx1[r + 1] * inv);
  }
  asm volatile("s_waitcnt lgkmcnt(0)" ::: "memory");
  // each lane stores 4 x 16B: q row = lane>>1, dh chunks (lane&1)*4 + 0..3
  const int q2 = lane >> 1;
#pragma unroll
  for (int i = 0; i < 4; i++) {
    const int ch = (lane & 1) * 4 + i;
    u16x8 vv = *(const u16x8*)&Tl[q2][ch * 8];
    *(u16x8*)&cx[(size_t)(tok0 + q2) * D_MODEL + h * DH + ch * 8] = vv;
  }
}

// ---------------------------------------------------------------------------
extern "C" void kernel_launch(void* const* d_in, const int* in_sizes, int n_in,
                              void* d_out, int out_size, void* d_ws,
                              size_t ws_size, hipStream_t stream) {
  const float* x  = (const float*)d_in[0];
  const float* Wq = (const float*)d_in[1];
  const float* Wk = (const float*)d_in[2];
  const float* Wv = (const float*)d_in[3];
  const float* Wo = (const float*)d_in[4];
  const float* bo = (const float*)d_in[5];
  float* out = (float*)d_out;

  // workspace (bf16 elements): xb 4M | wqb,wkb,wvb,wob 1M each | qb,kb,vt,cx 4M
  unsigned short* xb  = (unsigned short*)d_ws;
  unsigned short* wqb = xb  + (size_t)M_TOT * D_MODEL;
  unsigned short* wkb = wqb + (size_t)D_MODEL * D_MODEL;
  unsigned short* wvb = wkb + (size_t)D_MODEL * D_MODEL;
  unsigned short* wob = wvb + (size_t)D_MODEL * D_MODEL;
  unsigned short* qb  = wob + (size_t)D_MODEL * D_MODEL;
  unsigned short* kb  = qb  + (size_t)M_TOT * D_MODEL;
  unsigned short* vt  = kb  + (size_t)M_TOT * D_MODEL;
  unsigned short* cx  = vt  + (size_t)M_TOT * D_MODEL;

  to_bf16_all<<<4096, 256, 0, stream>>>(x, Wq, Wk, Wv, Wo, xb, wqb, wkb, wvb,
                                        wob);
  gemm_qkv<<<dim3(D_MODEL / 128, M_TOT / 128, 3), 256, 0, stream>>>(
      xb, wqb, wkb, wvb, qb, kb, vt);
  attn_v4<<<dim3(2048), 64, 0, stream>>>(qb, kb, vt, cx);
  gemm_out<<<dim3(D_MODEL / 128, M_TOT / 128), 256, 0, stream>>>(cx, wob, out,
                                                                 bo);
}

// Round 7
// 123.194 us; speedup vs baseline: 1.1880x; 1.1880x over previous
//
#include <hip/hip_runtime.h>
#include <hip/hip_bf16.h>

// Problem constants (MultiHeadAttention, B=2, S=2048, D=1024, H=16)
#define B_SZ    2
#define S_LEN   2048
#define D_MODEL 1024
#define H_NUM   16
#define DH      64
#define M_TOT   (B_SZ * S_LEN)   // 4096 tokens

// scale = S^-0.5 (faithful bug) folded with log2(e) for exp2-domain softmax
#define QSCALE (0.022097086912079608f * 1.4426950408889634f)

typedef __attribute__((ext_vector_type(8)))  short          bf16x8;
typedef __attribute__((ext_vector_type(4)))  float          f32x4;
typedef __attribute__((ext_vector_type(16))) float          f32x16;
typedef __attribute__((ext_vector_type(8)))  unsigned short u16x8;
typedef __attribute__((ext_vector_type(4)))  unsigned short u16x4;

__device__ inline unsigned short f2bf(float f) {
  unsigned int u = __float_as_uint(f);
  u += 0x7fffu + ((u >> 16) & 1u);   // RNE (no NaN inputs here)
  return (unsigned short)(u >> 16);
}

__device__ inline float bf2f(unsigned short u) {
  return __uint_as_float(((unsigned)u) << 16);
}

__device__ inline float fexp2(float x) {
#if __has_builtin(__builtin_amdgcn_exp2f)
  return __builtin_amdgcn_exp2f(x);
#else
  return exp2f(x);
#endif
}

__device__ inline unsigned cvt_pk_bf16(float lo, float hi) {
  unsigned r;
  asm("v_cvt_pk_bf16_f32 %0, %1, %2" : "=v"(r) : "v"(lo), "v"(hi));
  return r;
}

// async global->LDS, 16B per lane. LDS dest = wave-uniform base + lane*16.
__device__ inline void gload16(const void* g, void* l) {
  __builtin_amdgcn_global_load_lds(
      (const __attribute__((address_space(1))) void*)g,
      (__attribute__((address_space(3))) void*)l, 16, 0, 0);
}

// ---------------------------------------------------------------------------
// fp32 -> bf16 conversion for x, Wq, Wk, Wv, Wo (8M elements, 8 per thread)
// ---------------------------------------------------------------------------
__global__ __launch_bounds__(256) void to_bf16_all(
    const float* __restrict__ x, const float* __restrict__ wq,
    const float* __restrict__ wk, const float* __restrict__ wv,
    const float* __restrict__ wo, unsigned short* __restrict__ xb,
    unsigned short* __restrict__ wqb, unsigned short* __restrict__ wkb,
    unsigned short* __restrict__ wvb, unsigned short* __restrict__ wob) {
  const size_t i = ((size_t)blockIdx.x * 256 + threadIdx.x) * 8;
  const float* src;
  unsigned short* dst;
  size_t off;
  if (i < 4194304)      { src = x;  dst = xb;  off = i; }
  else if (i < 5242880) { src = wq; dst = wqb; off = i - 4194304; }
  else if (i < 6291456) { src = wk; dst = wkb; off = i - 5242880; }
  else if (i < 7340032) { src = wv; dst = wvb; off = i - 6291456; }
  else                  { src = wo; dst = wob; off = i - 7340032; }
  f32x4 a = *(const f32x4*)(src + off);
  f32x4 b = *(const f32x4*)(src + off + 4);
  u16x8 o;
#pragma unroll
  for (int j = 0; j < 4; j++) { o[j] = f2bf(a[j]); o[4 + j] = f2bf(b[j]); }
  *(u16x8*)(dst + off) = o;
}

// ---------------------------------------------------------------------------
// bf16 NT-GEMM core: acc += A[128 rows @ mbase] * W[128 rows @ nbase]^T.
// Double-buffered global_load_lds(16) staging with counted vmcnt(4) + raw
// s_barrier pairs (prefetch stays in flight across barriers; no full drain).
// Linear LDS + XOR chunk swizzle (pre-swizzled source, swizzled read).
// ---------------------------------------------------------------------------
__device__ __forceinline__ void gemm_core(const unsigned short* __restrict__ A,
                                          const unsigned short* __restrict__ W,
                                          unsigned short (*Al)[128][32],
                                          unsigned short (*Bl)[128][32],
                                          int mbase, int nbase,
                                          f32x4 acc[4][4]) {
  const int tid  = threadIdx.x;
  const int lane = tid & 63;
  const int wid  = tid >> 6;
  const int wr   = wid >> 1, wc = wid & 1;
  const int g    = lane >> 4, lr = lane & 15;

  const int r0 = tid >> 2;                        // 0..63 staging row
  const int cg = (tid & 3) ^ ((tid >> 3) & 3);    // swizzled source chunk

  const unsigned short* Abase = A + (size_t)(mbase + r0) * D_MODEL + cg * 8;
  const unsigned short* Wbase = W + (size_t)(nbase + r0) * D_MODEL + cg * 8;
  char* ldsA0 = (char*)Al + wid * 1024;  // buffer stride 8192
  char* ldsB0 = (char*)Bl + wid * 1024;

  // prologue: tile 0 -> buf 0
  gload16(Abase, ldsA0);
  gload16(Abase + (size_t)64 * D_MODEL, ldsA0 + 4096);
  gload16(Wbase, ldsB0);
  gload16(Wbase + (size_t)64 * D_MODEL, ldsB0 + 4096);

  const int NKT = D_MODEL / 32;
  for (int kt = 0; kt < NKT; ++kt) {
    const int cur = kt & 1;
    if (kt + 1 < NKT) {  // prefetch next tile into other buffer
      const unsigned short* As = Abase + (kt + 1) * 32;
      const unsigned short* Ws = Wbase + (kt + 1) * 32;
      char* la = ldsA0 + (cur ^ 1) * 8192;
      char* lb = ldsB0 + (cur ^ 1) * 8192;
      gload16(As, la);
      gload16(As + (size_t)64 * D_MODEL, la + 4096);
      gload16(Ws, lb);
      gload16(Ws + (size_t)64 * D_MODEL, lb + 4096);
      asm volatile("s_waitcnt vmcnt(4)" ::: "memory");  // tile kt landed
    } else {
      asm volatile("s_waitcnt vmcnt(0)" ::: "memory");
    }
    __builtin_amdgcn_s_barrier();

    bf16x8 af[4], bfr[4];
#pragma unroll
    for (int i = 0; i < 4; i++) {
      const int ra = wr * 64 + i * 16 + lr;
      af[i] = *(const bf16x8*)&Al[cur][ra][(g ^ ((ra >> 1) & 3)) * 8];
      const int rb = wc * 64 + i * 16 + lr;
      bfr[i] = *(const bf16x8*)&Bl[cur][rb][(g ^ ((rb >> 1) & 3)) * 8];
    }
    __builtin_amdgcn_s_setprio(1);
#pragma unroll
    for (int i = 0; i < 4; i++)
#pragma unroll
      for (int j = 0; j < 4; j++)
        acc[i][j] = __builtin_amdgcn_mfma_f32_16x16x32_bf16(af[i], bfr[j],
                                                            acc[i][j], 0, 0, 0);
    __builtin_amdgcn_s_setprio(0);
    asm volatile("" ::: "memory");
    __builtin_amdgcn_s_barrier();  // buf[cur] free for next prefetch
  }
}

// ---------------------------------------------------------------------------
// Fused Q/K/V projection. grid (N/128, M/128, 3); z picks weight + epilogue.
// z=0 -> Q bf16 [M][D] PRE-SCALED by QSCALE; z=1 -> K bf16 [M][D];
// z=2 -> V transposed Vt[((b*H+h)*DH+d)*S + s].
// ---------------------------------------------------------------------------
__global__ __launch_bounds__(256) void gemm_qkv(
    const unsigned short* __restrict__ xb, const unsigned short* __restrict__ wqb,
    const unsigned short* __restrict__ wkb, const unsigned short* __restrict__ wvb,
    unsigned short* __restrict__ qb, unsigned short* __restrict__ kb,
    unsigned short* __restrict__ vt) {
  __shared__ unsigned short Al[2][128][32];
  __shared__ unsigned short Bl[2][128][32];
  const int z = blockIdx.z;
  const unsigned short* W = (z == 0) ? wqb : (z == 1) ? wkb : wvb;
  unsigned short* dst = (z == 0) ? qb : (z == 1) ? kb : vt;
  const float sc = (z == 0) ? QSCALE : 1.0f;

  f32x4 acc[4][4];
#pragma unroll
  for (int i = 0; i < 4; i++)
#pragma unroll
    for (int j = 0; j < 4; j++) acc[i][j] = (f32x4){0.f, 0.f, 0.f, 0.f};

  const int mbase = blockIdx.y * 128, nbase = blockIdx.x * 128;
  gemm_core(xb, W, Al, Bl, mbase, nbase, acc);

  const int lane = threadIdx.x & 63, wid = threadIdx.x >> 6;
  const int wr = wid >> 1, wc = wid & 1, g = lane >> 4, lr = lane & 15;
#pragma unroll
  for (int i = 0; i < 4; i++) {
#pragma unroll
    for (int j = 0; j < 4; j++) {
      const int mg0 = mbase + wr * 64 + i * 16 + g * 4;  // + r
      const int ng  = nbase + wc * 64 + j * 16 + lr;
      if (z < 2) {
#pragma unroll
        for (int r = 0; r < 4; r++)
          dst[(size_t)(mg0 + r) * D_MODEL + ng] = f2bf(acc[i][j][r] * sc);
      } else {
        const int hh = ng >> 6, dd = ng & 63;
        const int bb = mg0 >> 11, ss = mg0 & 2047;  // mg0 mult of 4
        u16x4 pk;
#pragma unroll
        for (int r = 0; r < 4; r++) pk[r] = f2bf(acc[i][j][r]);
        *(u16x4*)&dst[((size_t)((bb * H_NUM + hh) * DH + dd)) * S_LEN + ss] = pk;
      }
    }
  }
}

// ---------------------------------------------------------------------------
// Output projection: out[M][D] fp32 = cx * Wo^T + bo
// ---------------------------------------------------------------------------
__global__ __launch_bounds__(256) void gemm_out(
    const unsigned short* __restrict__ cx, const unsigned short* __restrict__ wob,
    float* __restrict__ out, const float* __restrict__ bo) {
  __shared__ unsigned short Al[2][128][32];
  __shared__ unsigned short Bl[2][128][32];
  f32x4 acc[4][4];
#pragma unroll
  for (int i = 0; i < 4; i++)
#pragma unroll
    for (int j = 0; j < 4; j++) acc[i][j] = (f32x4){0.f, 0.f, 0.f, 0.f};

  const int mbase = blockIdx.y * 128, nbase = blockIdx.x * 128;
  gemm_core(cx, wob, Al, Bl, mbase, nbase, acc);

  const int lane = threadIdx.x & 63, wid = threadIdx.x >> 6;
  const int wr = wid >> 1, wc = wid & 1, g = lane >> 4, lr = lane & 15;
#pragma unroll
  for (int i = 0; i < 4; i++) {
#pragma unroll
    for (int j = 0; j < 4; j++) {
      const int mg0 = mbase + wr * 64 + i * 16 + g * 4;
      const int ng  = nbase + wc * 64 + j * 16 + lr;
      const float bv = bo[ng];
#pragma unroll
      for (int r = 0; r < 4; r++)
        out[(size_t)(mg0 + r) * D_MODEL + ng] = acc[i][j][r] + bv;
    }
  }
}

// ---------------------------------------------------------------------------
// Block schedule for attn_v5: 24 entries per bh, longest-first.
// Unsplit qtiles 0..7 (part=2, direct write); qtiles 8..15 split into two
// kv-halves (part=0/1); partials merged by attn_combine.
// Encoding: qi | kt0<<8 | kt1<<16 | part<<24.
// ---------------------------------------------------------------------------
__device__ const unsigned att_sched[24] = {
    15u | (0u << 8)  | (16u << 16) | (0u << 24),
    15u | (16u << 8) | (32u << 16) | (1u << 24),
    7u  | (0u << 8)  | (16u << 16) | (2u << 24),
    14u | (0u << 8)  | (15u << 16) | (0u << 24),
    14u | (15u << 8) | (30u << 16) | (1u << 24),
    13u | (0u << 8)  | (14u << 16) | (0u << 24),
    13u | (14u << 8) | (28u << 16) | (1u << 24),
    6u  | (0u << 8)  | (14u << 16) | (2u << 24),
    12u | (0u << 8)  | (13u << 16) | (0u << 24),
    12u | (13u << 8) | (26u << 16) | (1u << 24),
    11u | (0u << 8)  | (12u << 16) | (0u << 24),
    11u | (12u << 8) | (24u << 16) | (1u << 24),
    5u  | (0u << 8)  | (12u << 16) | (2u << 24),
    10u | (0u << 8)  | (11u << 16) | (0u << 24),
    10u | (11u << 8) | (22u << 16) | (1u << 24),
    9u  | (0u << 8)  | (10u << 16) | (0u << 24),
    9u  | (10u << 8) | (20u << 16) | (1u << 24),
    4u  | (0u << 8)  | (10u << 16) | (2u << 24),
    8u  | (0u << 8)  | (9u << 16)  | (0u << 24),
    8u  | (9u << 8)  | (18u << 16) | (1u << 24),
    3u  | (0u << 8)  | (8u << 16)  | (2u << 24),
    2u  | (0u << 8)  | (6u << 16)  | (2u << 24),
    1u  | (0u << 8)  | (4u << 16)  | (2u << 24),
    0u  | (0u << 8)  | (2u << 16)  | (2u << 24),
};

// ---------------------------------------------------------------------------
// Causal flash attention v5 = v3 compute path + split-KV load balancing.
// grid = 768 blocks (24 sched entries x 32 bh); 4 waves, 128 q-rows/block.
// S^T = mfma(K, Q): lane owns P-row of q = lane&31 (partner lane^32).
// ctx^T = mfma(Vt, P). Counted-vmcnt double-buffered K/V LDS staging.
// part=2: normalize, write cx. part=0/1: write unnormalized bf16 partial +
// (m,l) per row into Opart/ml for attn_combine.
// ---------------------------------------------------------------------------
__global__ __launch_bounds__(256) void attn_v5(
    const unsigned short* __restrict__ qb, const unsigned short* __restrict__ kb,
    const unsigned short* __restrict__ vt, unsigned short* __restrict__ cx,
    unsigned short* __restrict__ Opart, float* __restrict__ ml) {
  __shared__ alignas(16) char smem[32768];  // K dbuf | V dbuf; Tl overlays

  const int tid  = threadIdx.x;
  const int lane = tid & 63;
  const int w    = tid >> 6;
  const int hi   = lane >> 5;
  const int lq   = lane & 31;
  const int bid  = blockIdx.x;

  const unsigned ent = att_sched[bid >> 5];
  const int qi   = ent & 255;
  const int kt0  = (ent >> 8) & 255;
  const int kt1  = (ent >> 16) & 255;
  const int part = (ent >> 24) & 255;  // 2=direct, 0/1=split half
  const int bh   = bid & 31;
  const int b    = bh >> 4, h = bh & 15;

  const int qg0  = qi * 128 + w * 32;   // wave's q base within sequence
  const int tok0 = b * S_LEN + qg0;

  // staging: thread t -> row t>>3 (+32 for 2nd issue), chunk t&7 swizzled
  const int sr  = tid >> 3;
  const int scg = (tid & 7) ^ (sr & 7);
  const unsigned short* kbase =
      kb + (size_t)(b * S_LEN) * D_MODEL + h * DH + scg * 8;
  const unsigned short* vrow =
      vt + ((size_t)((b * H_NUM + h) * DH + sr)) * S_LEN + scg * 8;
  char* ldsK0 = smem + w * 1024;           // + buf*8192
  char* ldsV0 = smem + 16384 + w * 1024;   // + buf*8192

  // Q fragments: B-operand, col q = lane&31, k = hi*8+j within slice ks
  bf16x8 qf[4];
  {
    const unsigned short* qrow =
        qb + (size_t)(tok0 + lq) * D_MODEL + h * DH + hi * 8;
#pragma unroll
    for (int ks = 0; ks < 4; ks++) qf[ks] = *(const bf16x8*)(qrow + ks * 16);
  }

  f32x16 ctx0, ctx1;
#pragma unroll
  for (int r = 0; r < 16; r++) { ctx0[r] = 0.f; ctx1[r] = 0.f; }
  float m_run = -1e30f, l_run = 0.f;

  const int ndiag = 2 * qi;

  // prologue: stage tile kt0 into buf 0 (4 loads)
  {
    const unsigned short* sK = kbase + (size_t)(kt0 * 64 + sr) * D_MODEL;
    gload16(sK, ldsK0);
    gload16(sK + (size_t)32 * D_MODEL, ldsK0 + 4096);
    const unsigned short* sV = vrow + kt0 * 64;
    gload16(sV, ldsV0);
    gload16(sV + (size_t)32 * S_LEN, ldsV0 + 4096);
  }

  int ti = 0;
  for (int kt = kt0; kt < kt1; ++kt, ++ti) {
    const int cur = ti & 1;
    if (kt + 1 < kt1) {  // prefetch next tile into other buffer
      const int nb = cur ^ 1;
      const unsigned short* sK = kbase + (size_t)((kt + 1) * 64 + sr) * D_MODEL;
      gload16(sK, ldsK0 + nb * 8192);
      gload16(sK + (size_t)32 * D_MODEL, ldsK0 + nb * 8192 + 4096);
      const unsigned short* sV = vrow + (kt + 1) * 64;
      gload16(sV, ldsV0 + nb * 8192);
      gload16(sV + (size_t)32 * S_LEN, ldsV0 + nb * 8192 + 4096);
      asm volatile("s_waitcnt vmcnt(4)" ::: "memory");  // tile kt landed
    } else {
      asm volatile("s_waitcnt vmcnt(0)" ::: "memory");
    }
    __builtin_amdgcn_s_barrier();

    const char* Kc = smem + cur * 8192;
    const char* Vc = smem + 16384 + cur * 8192;

    // ---- S^T = K Q^T : lane holds q=lq, 32 of 64 kv (partner l^32) ----
    f32x16 s0, s1;
#pragma unroll
    for (int r = 0; r < 16; r++) { s0[r] = 0.f; s1[r] = 0.f; }
    __builtin_amdgcn_s_setprio(1);
#pragma unroll
    for (int ks = 0; ks < 4; ks++) {
      const int c = ((ks * 2 + hi) ^ (lq & 7)) * 16;  // byte offset
      bf16x8 k0 = *(const bf16x8*)(Kc + lq * 128 + c);
      bf16x8 k1 = *(const bf16x8*)(Kc + (32 + lq) * 128 + c);
      s0 = __builtin_amdgcn_mfma_f32_32x32x16_bf16(k0, qf[ks], s0, 0, 0, 0);
      s1 = __builtin_amdgcn_mfma_f32_32x32x16_bf16(k1, qf[ks], s1, 0, 0, 0);
    }
    __builtin_amdgcn_s_setprio(0);

    // ---- causal mask (diagonal tiles only; uniform branch) ----
    if (kt >= ndiag) {
      const int relq = qg0 + lq - kt * 64 - 4 * hi;
#pragma unroll
      for (int r = 0; r < 16; r++) {
        const int ko = (r & 3) + 8 * (r >> 2);
        s0[r] = (ko > relq) ? -1e30f : s0[r];
        s1[r] = (ko + 32 > relq) ? -1e30f : s1[r];
      }
    }

    // ---- row max: depth-4 tree + one cross-half exchange ----
    float tm[8];
#pragma unroll
    for (int j = 0; j < 8; j++)
      tm[j] = fmaxf(fmaxf(s0[j], s0[j + 8]), fmaxf(s1[j], s1[j + 8]));
#pragma unroll
    for (int j = 0; j < 4; j++) tm[j] = fmaxf(tm[j], tm[j + 4]);
    float pmax = fmaxf(fmaxf(tm[0], tm[2]), fmaxf(tm[1], tm[3]));
    pmax = fmaxf(pmax, __shfl_xor(pmax, 32));

    // ---- defer-max rescale (T13, THR=8 in log2 domain) ----
    if (__any(pmax > m_run + 8.0f)) {
      const float mnew = fmaxf(m_run, pmax);
      const float al   = fexp2(m_run - mnew);
      m_run = mnew;
      l_run *= al;
#pragma unroll
      for (int r = 0; r < 16; r++) { ctx0[r] *= al; ctx1[r] *= al; }
    }

    // ---- P = exp2(S'-m) per 16-kv slice: pack in-reg, PV mfma ----
    float lsAcc[4];
#pragma unroll
    for (int ks = 0; ks < 4; ks++) {
      float p[8];
#pragma unroll
      for (int j = 0; j < 8; j++) {
        const int r = (ks & 1) * 8 + j;
        const float sv = (ks < 2) ? s0[r] : s1[r];
        p[j] = fexp2(sv - m_run);
      }
      lsAcc[ks] = ((p[0] + p[1]) + (p[2] + p[3])) +
                  ((p[4] + p[5]) + (p[6] + p[7]));
      const unsigned w01 = cvt_pk_bf16(p[0], p[1]);
      const unsigned w23 = cvt_pk_bf16(p[2], p[3]);
      const unsigned w45 = cvt_pk_bf16(p[4], p[5]);
      const unsigned w67 = cvt_pk_bf16(p[6], p[7]);
      const unsigned x01 = __shfl_xor(w01, 32);
      const unsigned x23 = __shfl_xor(w23, 32);
      const unsigned x45 = __shfl_xor(w45, 32);
      const unsigned x67 = __shfl_xor(w67, 32);
      union { unsigned u[4]; bf16x8 v; } pw;
      pw.u[0] = hi ? x45 : w01;
      pw.u[1] = hi ? x67 : w23;
      pw.u[2] = hi ? w45 : x01;
      pw.u[3] = hi ? w67 : x23;
      const int c = ((ks * 2 + hi) ^ (lq & 7)) * 16;  // byte offset
      bf16x8 v0 = *(const bf16x8*)(Vc + lq * 128 + c);
      bf16x8 v1 = *(const bf16x8*)(Vc + (32 + lq) * 128 + c);
      __builtin_amdgcn_s_setprio(1);
      ctx0 = __builtin_amdgcn_mfma_f32_32x32x16_bf16(v0, pw.v, ctx0, 0, 0, 0);
      ctx1 = __builtin_amdgcn_mfma_f32_32x32x16_bf16(v1, pw.v, ctx1, 0, 0, 0);
      __builtin_amdgcn_s_setprio(0);
    }
    l_run += (lsAcc[0] + lsAcc[1]) + (lsAcc[2] + lsAcc[3]);
    asm volatile("" ::: "memory");
    __builtin_amdgcn_s_barrier();  // buf[cur] free for next prefetch
  }

  // ---- epilogue: transpose via LDS (Tl overlays K/V buffers) ----
  unsigned short (*Tl)[32][72] = (unsigned short (*)[32][72])smem;
  const float lfull = l_run + __shfl_xor(l_run, 32);
  const float inv   = (part == 2) ? (1.0f / lfull) : 1.0f;
#pragma unroll
  for (int rp = 0; rp < 8; rp++) {
    const int r  = rp * 2;
    const int d0 = (r & 3) + 8 * (r >> 2) + 4 * hi;  // even; pair (d0, d0+1)
    *(unsigned*)&Tl[w][lq][d0] = cvt_pk_bf16(ctx0[r] * inv, ctx0[r + 1] * inv);
    *(unsigned*)&Tl[w][lq][32 + d0] =
        cvt_pk_bf16(ctx1[r] * inv, ctx1[r + 1] * inv);
  }
  asm volatile("s_waitcnt lgkmcnt(0)" ::: "memory");
  const int q2 = lane >> 1;  // q row within wave tile
  if (part == 2) {
    // direct: each lane stores 4 x 16B to cx
#pragma unroll
    for (int i = 0; i < 4; i++) {
      const int ch = (lane & 1) * 4 + i;
      u16x8 vv = *(const u16x8*)&Tl[w][q2][ch * 8];
      *(u16x8*)&cx[(size_t)(tok0 + q2) * D_MODEL + h * DH + ch * 8] = vv;
    }
  } else {
    const int pidx = (qi - 8) * 2 + part;
    unsigned short* od =
        Opart + ((size_t)(pidx * 32 + bh) * 128 + w * 32 + q2) * 64;
#pragma unroll
    for (int i = 0; i < 4; i++) {
      const int ch = (lane & 1) * 4 + i;
      u16x8 vv = *(const u16x8*)&Tl[w][q2][ch * 8];
      *(u16x8*)&od[ch * 8] = vv;
    }
    if (hi == 0) {  // per q-row (m, l)
      float2 v2 = make_float2(m_run, lfull);
      *(float2*)&ml[((size_t)(pidx * 32 + bh) * 128 + w * 32 + lq) * 2] = v2;
    }
  }
}

// ---------------------------------------------------------------------------
// Merge split-KV partials for qtiles 8..15 and write cx.
// 262144 threads: 8 threads per (qi8, bh, row); each handles 8 dh.
// ---------------------------------------------------------------------------
__global__ __launch_bounds__(256) void attn_combine(
    const unsigned short* __restrict__ Opart, const float* __restrict__ ml,
    unsigned short* __restrict__ cx) {
  const int gid    = blockIdx.x * 256 + threadIdx.x;
  const int sub    = gid & 7;
  const int row_id = gid >> 3;          // 0..32767
  const int row    = row_id & 127;
  const int bh     = (row_id >> 7) & 31;
  const int qi8    = row_id >> 12;      // 0..7 (qi = qi8+8)
  const int pA = qi8 * 2, pB = qi8 * 2 + 1;

  const size_t ra = (size_t)(pA * 32 + bh) * 128 + row;
  const size_t rb = (size_t)(pB * 32 + bh) * 128 + row;
  const float mA = ml[ra * 2], lA = ml[ra * 2 + 1];
  const float mB = ml[rb * 2], lB = ml[rb * 2 + 1];
  const float m  = fmaxf(mA, mB);
  const float wA = fexp2(mA - m), wB = fexp2(mB - m);
  const float inv = 1.0f / (lA * wA + lB * wB);

  u16x8 a = *(const u16x8*)&Opart[ra * 64 + sub * 8];
  u16x8 c = *(const u16x8*)&Opart[rb * 64 + sub * 8];
  u16x8 o;
#pragma unroll
  for (int j = 0; j < 8; j++)
    o[j] = f2bf((bf2f(a[j]) * wA + bf2f(c[j]) * wB) * inv);

  const int b = bh >> 4, h = bh & 15;
  const int tok = b * S_LEN + (qi8 + 8) * 128 + row;
  *(u16x8*)&cx[(size_t)tok * D_MODEL + h * DH + sub * 8] = o;
}

// ---------------------------------------------------------------------------
extern "C" void kernel_launch(void* const* d_in, const int* in_sizes, int n_in,
                              void* d_out, int out_size, void* d_ws,
                              size_t ws_size, hipStream_t stream) {
  const float* x  = (const float*)d_in[0];
  const float* Wq = (const float*)d_in[1];
  const float* Wk = (const float*)d_in[2];
  const float* Wv = (const float*)d_in[3];
  const float* Wo = (const float*)d_in[4];
  const float* bo = (const float*)d_in[5];
  float* out = (float*)d_out;

  // workspace (bf16 elements): xb 4M | wqb,wkb,wvb,wob 1M each | qb,kb,vt,cx 4M
  // After gemm_qkv, xb is reused as Opart (exactly 4M bf16) and wqb as ml.
  unsigned short* xb  = (unsigned short*)d_ws;
  unsigned short* wqb = xb  + (size_t)M_TOT * D_MODEL;
  unsigned short* wkb = wqb + (size_t)D_MODEL * D_MODEL;
  unsigned short* wvb = wkb + (size_t)D_MODEL * D_MODEL;
  unsigned short* wob = wvb + (size_t)D_MODEL * D_MODEL;
  unsigned short* qb  = wob + (size_t)D_MODEL * D_MODEL;
  unsigned short* kb  = qb  + (size_t)M_TOT * D_MODEL;
  unsigned short* vt  = kb  + (size_t)M_TOT * D_MODEL;
  unsigned short* cx  = vt  + (size_t)M_TOT * D_MODEL;
  unsigned short* Opart = xb;          // 4M bf16 (dead after gemm_qkv)
  float*          ml    = (float*)wqb; // 512 KB   (dead after gemm_qkv)

  to_bf16_all<<<4096, 256, 0, stream>>>(x, Wq, Wk, Wv, Wo, xb, wqb, wkb, wvb,
                                        wob);
  gemm_qkv<<<dim3(D_MODEL / 128, M_TOT / 128, 3), 256, 0, stream>>>(
      xb, wqb, wkb, wvb, qb, kb, vt);
  attn_v5<<<dim3(768), 256, 0, stream>>>(qb, kb, vt, cx, Opart, ml);
  attn_combine<<<dim3(1024), 256, 0, stream>>>(Opart, ml, cx);
  gemm_out<<<dim3(D_MODEL / 128, M_TOT / 128), 256, 0, stream>>>(cx, wob, out,
                                                                 bo);
}